// Round 8
// baseline (64.472 us; speedup 1.0000x reference)
//
#include <hip/hip_runtime.h>
#include <hip/hip_bf16.h>

// Problem constants (fixed by the reference)
#define Bz 8
#define Cc 256
#define HWp 23104            // 152*152
#define Kk 1024
#define BK (Bz*Kk)
#define MARGIN_F 10.0f
#define BIGF 1e30f

typedef __attribute__((ext_vector_type(8))) short bf16x8;  // 8 bf16 = 4 VGPRs
typedef __attribute__((ext_vector_type(4))) float f32x4;   // MFMA 16x16 accumulator

__device__ __forceinline__ uint pk2(float a, float b) {
    return (uint)__hip_bfloat16_raw(__float2bfloat16(a)).x
         | ((uint)__hip_bfloat16_raw(__float2bfloat16(b)).x << 16);
}

// ---------------------------------------------------------------------------
// Kernel 0: DIRECT scattered gather with line reuse.
// R3/R4/R6 lesson: any full-plane stream reads 189 MB -> ~30us floor.  Only
// ~8 MB is needed; 1024 random draws touch ~339 of a plane's 361 64B lines,
// each line ~2.8x reused.  Block = (b, 4-channel group) owns ALL 1024 k's of
// its 4 planes -> the reuse is captured by MSHR-merge/L1/L2 (all 16 loads
// per thread concurrently outstanding), total line traffic ~47 MB from L3.
// Writes: per (k, block) one 8B chunk embr[k][c0..c0+3], written exactly
// once (partial-line byte-masked writes, correctness proven in R3/R4).
// 512 blocks x 256 thr = 2 blocks/CU, 16 independent loads/thread ILP.
// ---------------------------------------------------------------------------
__global__ __launch_bounds__(256) void direct_gather(
    const float* __restrict__ x, const int* __restrict__ ind,
    __hip_bfloat16* __restrict__ embr)
{
    int c0 = blockIdx.x * 4;                  // channel group 0..63
    int b  = blockIdx.y;
    const int*   indb = ind + b * Kk;
    const float* xb   = x + (size_t)b * Cc * HWp;
    #pragma unroll
    for (int q = 0; q < 4; ++q) {
        int k  = q * 256 + threadIdx.x;       // lanes = consecutive k
        int hw = indb[k];
        float v0 = xb[(size_t)(c0 + 0) * HWp + hw];
        float v1 = xb[(size_t)(c0 + 1) * HWp + hw];
        float v2 = xb[(size_t)(c0 + 2) * HWp + hw];
        float v3 = xb[(size_t)(c0 + 3) * HWp + hw];
        uint2 o;
        o.x = pk2(v0, v1);
        o.y = pk2(v2, v3);
        *(uint2*)((ushort*)embr + (size_t)(b * Kk + k) * Cc + c0) = o;
    }
}

// ---------------------------------------------------------------------------
// Kernel 1: rownorm — one wave per row (unchanged from R6).
// scl = 10/max(sqrt(ssq),eps); neg_min init (ws poisoned once by harness).
// ---------------------------------------------------------------------------
__global__ __launch_bounds__(256) void rownorm(
    const __hip_bfloat16* __restrict__ embr, float* __restrict__ scl,
    unsigned* __restrict__ neg)
{
    int row  = blockIdx.x * 4 + (threadIdx.x >> 6);
    int lane = threadIdx.x & 63;
    uint2 v = *((const uint2*)((const ushort*)embr + (size_t)row * Cc) + lane);
    float f0 = __uint_as_float(v.x << 16);
    float f1 = __uint_as_float(v.x & 0xffff0000u);
    float f2 = __uint_as_float(v.y << 16);
    float f3 = __uint_as_float(v.y & 0xffff0000u);
    float s = f0*f0 + f1*f1 + f2*f2 + f3*f3;
    #pragma unroll
    for (int off = 32; off; off >>= 1) s += __shfl_xor(s, off);
    if (lane == 0) {
        scl[row] = 10.0f / fmaxf(sqrtf(s), 1e-12f);
        neg[row] = __float_as_uint(BIGF);
    }
}

// ---------------------------------------------------------------------------
// Kernel 2: Gram via bf16 MFMA with LDS-staged panels (unchanged from R5/R6)
// + fused masked-min.  d2 = 200 - 2*scl_i*scl_j*Graw (||emb||^2 == 100 by
// construction), clamped >= 0 BEFORE the uint-bit atomicMin.
// ---------------------------------------------------------------------------
#define TILE 128
__global__ __launch_bounds__(256) void gram_mfma_min(
    const __hip_bfloat16* __restrict__ emb, const float* __restrict__ scl,
    const int* __restrict__ mask, unsigned* __restrict__ neg)
{
    __shared__ __align__(16) short As[TILE * 64];   // 16 KB, row-major [128][64]
    __shared__ __align__(16) short Bs[TILE * 64];   // 16 KB
    int b  = blockIdx.z;
    int i0 = blockIdx.y * TILE;
    int j0 = blockIdx.x * TILE;
    int w  = threadIdx.x >> 6, l = threadIdx.x & 63;
    int wr = w >> 1, wc = w & 1;          // wave's 64x64 quadrant
    int lr = l & 15, lg = l >> 4;         // lane row / k-group (for MFMA frags)

    const short* E  = (const short*)emb + (size_t)b * Kk * Cc;
    const short* EA = E + (size_t)i0 * Cc;
    const short* EB = E + (size_t)j0 * Cc;

    // staging: instruction t (=w*4+q) fills LDS rows t*8..t*8+7;
    // lane l -> row offset l/8, slot l%8; source k-chunk = (l%8) ^ (l/8).
    int lrow = l >> 3;
    int lsub = (l & 7) ^ lrow;

    f32x4 acc[4][4] = {};
    for (int k0 = 0; k0 < Cc; k0 += 64) {
        #pragma unroll
        for (int q = 0; q < 4; ++q) {
            int t = w * 4 + q;
            int r = t * 8 + lrow;
            __builtin_amdgcn_global_load_lds(
                (const __attribute__((address_space(1))) void*)(EA + (size_t)r * Cc + k0 + lsub * 8),
                (__attribute__((address_space(3))) void*)&As[t * 512], 16, 0, 0);
            __builtin_amdgcn_global_load_lds(
                (const __attribute__((address_space(1))) void*)(EB + (size_t)r * Cc + k0 + lsub * 8),
                (__attribute__((address_space(3))) void*)&Bs[t * 512], 16, 0, 0);
        }
        __syncthreads();

        #pragma unroll
        for (int kk = 0; kk < 2; ++kk) {
            bf16x8 af[4], bf[4];
            #pragma unroll
            for (int f = 0; f < 4; ++f) {
                int ra = wr * 64 + f * 16 + lr;
                af[f] = *(const bf16x8*)&As[ra * 64 + (((kk * 4 + lg) ^ (ra & 7)) << 3)];
                int rb = wc * 64 + f * 16 + lr;
                bf[f] = *(const bf16x8*)&Bs[rb * 64 + (((kk * 4 + lg) ^ (rb & 7)) << 3)];
            }
            #pragma unroll
            for (int fi = 0; fi < 4; ++fi)
                #pragma unroll
                for (int fj = 0; fj < 4; ++fj)
                    acc[fi][fj] = __builtin_amdgcn_mfma_f32_16x16x32_bf16(
                                      af[fi], bf[fj], acc[fi][fj], 0, 0, 0);
        }
        __syncthreads();
    }

    const int* mb = mask + b * Kk;
    float cjv[4]; int jgv[4]; bool jva[4];
    #pragma unroll
    for (int fj = 0; fj < 4; ++fj) {
        int jg = j0 + wc*64 + fj*16 + lr;
        jgv[fj] = jg;
        cjv[fj] = scl[b * Kk + jg];
        jva[fj] = (mb[jg] != 0);
    }
    #pragma unroll
    for (int fi = 0; fi < 4; ++fi) {
        #pragma unroll
        for (int r = 0; r < 4; ++r) {
            int ig = i0 + wr*64 + fi*16 + 4*lg + r;
            float ci = scl[b * Kk + ig];
            float m = BIGF;
            #pragma unroll
            for (int fj = 0; fj < 4; ++fj) {
                float d2 = fmaxf(200.0f - 2.0f * ci * cjv[fj] * acc[fi][fj][r], 0.0f);
                bool ok = jva[fj] && (jgv[fj] != ig);
                m = ok ? fminf(m, d2) : m;
            }
            #pragma unroll
            for (int off = 1; off < 16; off <<= 1)
                m = fminf(m, __shfl_xor(m, off));
            if (lr == 0)
                atomicMin(&neg[b * Kk + ig], __float_as_uint(m));
        }
    }
}

// ---------------------------------------------------------------------------
// Kernel 3: hinge = max(margin - sqrt(min_d2), 0) over valid anchors; mean.
// ---------------------------------------------------------------------------
__global__ __launch_bounds__(1024) void hinge_final(
    const unsigned* __restrict__ neg, const int* __restrict__ mask,
    float* __restrict__ out)
{
    float h = 0.f, v = 0.f;
    for (int i = threadIdx.x; i < BK; i += 1024) {
        if (mask[i] != 0) {
            float d = sqrtf(__uint_as_float(neg[i]));
            h += fmaxf(MARGIN_F - d, 0.f);
            v += 1.f;
        }
    }
    #pragma unroll
    for (int off = 32; off; off >>= 1) {
        h += __shfl_xor(h, off);
        v += __shfl_xor(v, off);
    }
    __shared__ float sh[16], sv[16];
    int w = threadIdx.x >> 6;
    if ((threadIdx.x & 63) == 0) { sh[w] = h; sv[w] = v; }
    __syncthreads();
    if (threadIdx.x == 0) {
        float H = 0.f, V = 0.f;
        #pragma unroll
        for (int i = 0; i < 16; ++i) { H += sh[i]; V += sv[i]; }
        out[0] = H / V;
    }
}

// ---------------------------------------------------------------------------
extern "C" void kernel_launch(void* const* d_in, const int* in_sizes, int n_in,
                              void* d_out, int out_size, void* d_ws, size_t ws_size,
                              hipStream_t stream) {
    const float* x     = (const float*)d_in[0];   // [B,C,H,W] fp32
    const int*   ind   = (const int*)d_in[1];     // [B,K] int32
    const int*   mask  = (const int*)d_in[2];     // [B,K] int32
    float* out = (float*)d_out;

    // ws layout: embr bf16 [B*K][C] (4 MB) | scl f32 [B*K] | neg u32 [B*K]
    __hip_bfloat16* embr = (__hip_bfloat16*)d_ws;
    float*    scl = (float*)((char*)d_ws + (size_t)BK * Cc * sizeof(__hip_bfloat16));
    unsigned* neg = (unsigned*)(scl + BK);

    dim3 g0(Cc / 4, Bz);                      // (64 channel groups, 8 batches)
    direct_gather<<<g0, 256, 0, stream>>>(x, ind, embr);
    rownorm<<<BK / 4, 256, 0, stream>>>(embr, scl, neg);
    dim3 g2(Kk / TILE, Kk / TILE, Bz);
    gram_mfma_min<<<g2, 256, 0, stream>>>(embr, scl, mask, neg);
    hinge_final<<<1, 1024, 0, stream>>>(neg, mask, out);
}